// Round 27
// baseline (86.497 us; speedup 1.0000x reference)
//
#include <hip/hip_runtime.h>
#include <hip/hip_bf16.h>

typedef __bf16 bf16x8 __attribute__((ext_vector_type(8)));
typedef __bf16 bf16x4 __attribute__((ext_vector_type(4)));
typedef float  f32x4  __attribute__((ext_vector_type(4)));

#define V_TOTAL 32768
#define NT      512        // 8 waves/block
#define NV      16         // v-chunks of 64 positions per block
#define NBLK    512        // 2 blocks/CU -> 4 waves/SIMD (R26 insight: stall-bound at 2)

#define NKLDS   2                      // kt panels 0..1 in LDS; 2..7 in registers
#define W2_LDS  (NKLDS * 16384)        // 32768
#define H1_LDS  32768                  // single h1 panel (2-barrier schedule)
#define RED_LDS 2048                   // red[512], barrier-ordered single buffer
#define LDS_TOT (W2_LDS + H1_LDS + RED_LDS)   // 67584 -> 2 blocks/CU (135168 < 160K)

// async global->LDS, 16B/lane; LDS dest = wave-uniform base (+lane*16 by HW)
#define GLOAD_LDS16(g, l) __builtin_amdgcn_global_load_lds( \
    (const __attribute__((address_space(1))) void*)(g),     \
    (__attribute__((address_space(3))) void*)(l), 16, 0, 0)

// ---- prep: w2 fp32 -> bf16 in LDS-chunk order ----
// chunk c = kt*1024 + mt16*64 + ko*16 + row  ->  m = mt16*16+row, k = kt*32+ko*8+j
__global__ void w2_to_bf16(const float* __restrict__ w2, __bf16* __restrict__ w2b) {
    int i = blockIdx.x * 256 + threadIdx.x;   // 8*256*256 total
    int e = i >> 16, q = i & 65535, c = q >> 3, j = q & 7;
    int kt = c >> 10, mt16 = (c >> 6) & 15, ko = (c >> 4) & 3, row = c & 15;
    w2b[i] = (__bf16)w2[e * 65536 + (mt16 * 16 + row) * 256 + kt * 32 + ko * 8 + j];
}

__global__ __launch_bounds__(NT) void fused_mlp(
    const float* __restrict__ x,  const int* __restrict__ obj,
    const float* __restrict__ w1, const float* __restrict__ b1,
    const float* __restrict__ b2, const float* __restrict__ w3,
    const float* __restrict__ b3, const __bf16* __restrict__ w2b,
    float* __restrict__ out)
{
    extern __shared__ __align__(16) char smem[];
    char*  w2s = smem;                      // kt 0..1, chunk (kt*1024+mtile*64+koct*16+row)
    char*  h1t = smem + W2_LDS;             // single panel: chunk (kt*256 + nt*64 + lane)
    float* red = (float*)(smem + W2_LDS + H1_LDS);   // [512]

    const int t    = threadIdx.x;
    const int lane = t & 63;
    const int wv   = t >> 6;                // wave owns rows [wv*32, wv*32+32)
    const int llo  = lane & 15;
    const int lhi  = lane >> 4;
    const int b    = blockIdx.x >> 5;       // sample (32 blocks each)
    const int g    = blockIdx.x & 31;
    const int e    = __builtin_amdgcn_readfirstlane(obj[b]);
    const __bf16* w2sw = w2b + (size_t)e * 65536;   // pre-swizzled chunk order

    // ---- stage kt 0..1 of W2[e] (32 KB): coalesced 1KB/wave loads ----
    #pragma unroll
    for (int it = 0; it < 4; ++it) {
        int c0 = it * NT + wv * 64;         // wave-uniform chunk base
        GLOAD_LDS16(w2sw + c0 * 8 + lane * 8, w2s + c0 * 16);
    }

    // ---- kt 2..7 A-frags in registers (48 VGPRs) ----
    bf16x8 aar[6][2];
    #pragma unroll
    for (int k2 = 0; k2 < 6; ++k2)
        #pragma unroll
        for (int mt = 0; mt < 2; ++mt) {
            int c = (2 + k2) * 1024 + (2 * wv + mt) * 64 + lane;
            aar[k2][mt] = *(const bf16x8*)(w2sw + c * 8);
        }

    // ---- L1 as MFMA: W1 A-frags + hoisted bias/weight frags, resident ----
    const float* w1e = w1 + e * 1536;
    bf16x8 aa1[2];
    f32x4  b1f[2], bv[2], wf[2];
    #pragma unroll
    for (int mt2 = 0; mt2 < 2; ++mt2) {
        const int m0 = (2 * wv + mt2) * 16;
        bf16x8 v = {};
        if (lhi == 0)
            #pragma unroll
            for (int j = 0; j < 6; ++j) v[j] = (__bf16)w1e[(m0 + llo) * 6 + j];
        aa1[mt2] = v;
        b1f[mt2] = *(const f32x4*)(b1 + e * 256 + m0 + lhi * 4);
        bv[mt2]  = *(const f32x4*)(b2 + e * 256 + m0 + lhi * 4);
        wf[mt2]  = *(const f32x4*)(w3 + e * 256 + m0 + lhi * 4);
    }
    const float b3e = b3[e];
    const float* xe = x + (size_t)b * 6 * V_TOTAL;

    bf16x8 xf[4];
    auto load_x = [&](int ic) {             // xf <- x(chunk ic), pre-cvt bf16
        #pragma unroll
        for (int pt = 0; pt < 4; ++pt) {
            bf16x8 v = {};
            #pragma unroll
            for (int i = 0; i < 6; ++i)
                v[i] = (__bf16)xe[i * V_TOTAL + (g * NV + ic) * 64 + pt * 16 + llo];
            xf[pt] = v;
        }
    };
    auto do_l1 = [&]() {                    // h1 = relu(W1 x + b1), MFMA
        #pragma unroll
        for (int mt2 = 0; mt2 < 2; ++mt2) {
            const int o = (2 * wv + mt2) * 2 + (lhi >> 1);   // m-octet 0..31
            char* wbase = h1t + (o >> 2) * 4096 + (o & 3) * 256
                              + llo * 16 + (lhi & 1) * 8;
            #pragma unroll
            for (int pt = 0; pt < 4; ++pt) {
                f32x4 h = __builtin_amdgcn_mfma_f32_16x16x32_bf16(
                    aa1[mt2], xf[pt], b1f[mt2], 0, 0, 0);
                bf16x4 pk;
                #pragma unroll
                for (int r = 0; r < 4; ++r) pk[r] = (__bf16)fmaxf(h[r], 0.f);
                *(bf16x4*)(wbase + pt * 1024) = pk;
            }
        }
    };

    load_x(0);

    for (int iv = 0; iv < NV; ++iv) {
        // ---- layer 1 into h1 (single panel; prior readers done at bar2) ----
        do_l1();
        if (iv + 1 < NV) load_x(iv + 1);   // overlaps with L2 phase below
        __syncthreads();   // bar1: h1 ready (iv==0: W2 staging drained too)

        // ---- layer 2: kt 0..1 A from LDS, kt 2..7 A from registers ----
        f32x4 acc[2][4];
        #pragma unroll
        for (int mt = 0; mt < 2; ++mt)
            #pragma unroll
            for (int nt = 0; nt < 4; ++nt) acc[mt][nt] = bv[mt];
        const char* abase = w2s + wv * 2048 + lane * 16;
        const char* bbase = h1t + lane * 16;
        #pragma unroll
        for (int kt = 0; kt < 2; ++kt) {
            bf16x8 bb[4];
            #pragma unroll
            for (int nt = 0; nt < 4; ++nt)
                bb[nt] = *(const bf16x8*)(bbase + kt * 4096 + nt * 1024);
            #pragma unroll
            for (int mt = 0; mt < 2; ++mt) {
                const bf16x8 aw = *(const bf16x8*)(abase + kt * 16384 + mt * 1024);
                #pragma unroll
                for (int nt = 0; nt < 4; ++nt)
                    acc[mt][nt] = __builtin_amdgcn_mfma_f32_16x16x32_bf16(
                        aw, bb[nt], acc[mt][nt], 0, 0, 0);
            }
        }
        #pragma unroll
        for (int k2 = 0; k2 < 6; ++k2) {
            bf16x8 bb[4];
            #pragma unroll
            for (int nt = 0; nt < 4; ++nt)
                bb[nt] = *(const bf16x8*)(bbase + (2 + k2) * 4096 + nt * 1024);
            #pragma unroll
            for (int mt = 0; mt < 2; ++mt)
                #pragma unroll
                for (int nt = 0; nt < 4; ++nt)
                    acc[mt][nt] = __builtin_amdgcn_mfma_f32_16x16x32_bf16(
                        aar[k2][mt], bb[nt], acc[mt][nt], 0, 0, 0);
        }

        // ---- layer 3 partials into red ----
        float p[4];
        #pragma unroll
        for (int nt = 0; nt < 4; ++nt) {
            float s = 0.f;
            #pragma unroll
            for (int mt = 0; mt < 2; ++mt)
                #pragma unroll
                for (int j = 0; j < 4; ++j)
                    s = fmaf(wf[mt][j], fmaxf(acc[mt][nt][j], 0.f), s);
            s += __shfl_xor(s, 16, 64);
            s += __shfl_xor(s, 32, 64);
            p[nt] = s;
        }
        if (lane < 16)
            #pragma unroll
            for (int nt = 0; nt < 4; ++nt)
                red[wv * 64 + nt * 16 + lane] = p[nt];
        __syncthreads();   // bar2: red ready; h1 reads done (next L1 may overwrite)

        if (t < 64) {      // out-write; red reused only after next bar1 -> safe
            float s = b3e;
            #pragma unroll
            for (int w8 = 0; w8 < 8; ++w8) s += red[w8 * 64 + t];
            out[(size_t)b * V_TOTAL + (g * NV + iv) * 64 + t] = s;
        }
    }
}

extern "C" void kernel_launch(void* const* d_in, const int* in_sizes, int n_in,
                              void* d_out, int out_size, void* d_ws, size_t ws_size,
                              hipStream_t stream) {
    const float* x   = (const float*)d_in[0];
    const int*   obj = (const int*)d_in[1];
    const float* w1  = (const float*)d_in[2];
    const float* b1  = (const float*)d_in[3];
    const float* w2  = (const float*)d_in[4];
    const float* b2  = (const float*)d_in[5];
    const float* w3  = (const float*)d_in[6];
    const float* b3  = (const float*)d_in[7];
    float*  out = (float*)d_out;
    __bf16* w2b = (__bf16*)d_ws;   // 8*256*256 bf16 = 1 MB, LDS-chunk order

    (void)hipFuncSetAttribute((const void*)fused_mlp,
                              hipFuncAttributeMaxDynamicSharedMemorySize, LDS_TOT);

    w2_to_bf16<<<2048, 256, 0, stream>>>(w2, w2b);
    fused_mlp<<<NBLK, NT, LDS_TOT, stream>>>(x, obj, w1, b1, b2, w3, b3, w2b, out);
}